// Round 17
// baseline (261.252 us; speedup 1.0000x reference)
//
#include <hip/hip_runtime.h>
#include <math.h>

#define ENC 128
#define PRED 256
#define JD 256      // joiner_dim
#define VOCAB 500
#define NPAD 512
#define BB 8
#define TT 256
#define UU 64

typedef __attribute__((ext_vector_type(8))) _Float16 f16x8;
typedef __attribute__((ext_vector_type(4))) float f32x4;

// branchless tanh: ~8 VALU ops, |err| few ulp (≪ fp16 quantization error).
static __device__ __forceinline__ float fast_tanh(float x) {
    float ax = fabsf(x);
    float e = __expf(2.0f * ax);
    float t = 1.0f - 2.0f / (e + 1.0f);
    return copysignf(t, x);
}

// ---- Kernel A (tiled): blocks 0..255 -> hf (8 rows each), 256..319 -> hg
//      (8 rows each), 320..351 -> w2f convert. Each hf/hg block stages its
//      8 x-rows in LDS and reuses every w1 row-chunk across all 8 outputs.
__global__ __launch_bounds__(256) void joiner_pre(const float* __restrict__ ft,
                                                  const float* __restrict__ gu,
                                                  const float* __restrict__ w1,
                                                  const float* __restrict__ w2,
                                                  float* __restrict__ hf,
                                                  float* __restrict__ hg,
                                                  _Float16* __restrict__ w2f) {
    __shared__ float xs[8 * PRED];           // 8 KB (hf uses 8*128 of it)
    const int bid = blockIdx.x;
    const int tid = threadIdx.x;             // output col j for hf/hg parts

    if (bid < 256) {                         // ---- hf: rows bid*8..+8, K=128
        const int r0 = bid * 8;
        {
            const int row = tid >> 5, c4 = (tid & 31) * 4;   // 8 x 32 float4
            *(float4*)&xs[row * ENC + c4] =
                *(const float4*)(ft + (size_t)(r0 + row) * ENC + c4);
        }
        __syncthreads();
        const float* wr = w1 + tid * (ENC + PRED);
        float acc[8] = {0.f, 0.f, 0.f, 0.f, 0.f, 0.f, 0.f, 0.f};
        for (int k = 0; k < ENC; k += 32) {
            float4 wc[8];
#pragma unroll
            for (int i = 0; i < 8; ++i) wc[i] = *(const float4*)(wr + k + i * 4);
#pragma unroll
            for (int r = 0; r < 8; ++r) {
                const float* xr = xs + r * ENC + k;
                float s = 0.f;
#pragma unroll
                for (int i = 0; i < 8; ++i)
                    s += wc[i].x * xr[i * 4] + wc[i].y * xr[i * 4 + 1] +
                         wc[i].z * xr[i * 4 + 2] + wc[i].w * xr[i * 4 + 3];
                acc[r] += s;
            }
        }
#pragma unroll
        for (int r = 0; r < 8; ++r) hf[(size_t)(r0 + r) * JD + tid] = acc[r];
    } else if (bid < 320) {                  // ---- hg: rows (bid-256)*8, K=256
        const int r0 = (bid - 256) * 8;
#pragma unroll
        for (int h = 0; h < 2; ++h) {
            const int u = h * 256 + tid;     // float4 unit 0..511
            const int row = u >> 6, c4 = (u & 63) * 4;       // 8 x 64 float4
            *(float4*)&xs[row * PRED + c4] =
                *(const float4*)(gu + (size_t)(r0 + row) * PRED + c4);
        }
        __syncthreads();
        const float* wr = w1 + tid * (ENC + PRED) + ENC;
        float acc[8] = {0.f, 0.f, 0.f, 0.f, 0.f, 0.f, 0.f, 0.f};
        for (int k = 0; k < PRED; k += 32) {
            float4 wc[8];
#pragma unroll
            for (int i = 0; i < 8; ++i) wc[i] = *(const float4*)(wr + k + i * 4);
#pragma unroll
            for (int r = 0; r < 8; ++r) {
                const float* xr = xs + r * PRED + k;
                float s = 0.f;
#pragma unroll
                for (int i = 0; i < 8; ++i)
                    s += wc[i].x * xr[i * 4] + wc[i].y * xr[i * 4 + 1] +
                         wc[i].z * xr[i * 4 + 2] + wc[i].w * xr[i * 4 + 3];
                acc[r] += s;
            }
        }
#pragma unroll
        for (int r = 0; r < 8; ++r) hg[(size_t)(r0 + r) * JD + tid] = acc[r];
    } else {                                 // ---- w2f: fp16 convert, pad 512
        const int base = (bid - 320) * 4096; // 16 elems/thread, no row-crossing
        const int e0 = base + tid * 16;
        const int row = e0 >> 8;
        union { _Float16 h[16]; uint4 v[2]; } o;
        if (row < VOCAB) {
#pragma unroll
            for (int i = 0; i < 16; i += 4) {
                float4 f = *(const float4*)(w2 + (size_t)row * JD + (e0 & 255) + i);
                o.h[i] = (_Float16)f.x; o.h[i + 1] = (_Float16)f.y;
                o.h[i + 2] = (_Float16)f.z; o.h[i + 3] = (_Float16)f.w;
            }
        } else {
#pragma unroll
            for (int i = 0; i < 16; ++i) o.h[i] = (_Float16)0.f;
        }
        *(uint4*)(w2f + e0) = o.v[0];
        *(uint4*)(w2f + e0 + 8) = o.v[1];
    }
}

// ---- Kernel B: out = tanh(hf+hg) @ w2^T, single-pass fp16 MFMA ----
// 256 threads (4 waves) per (bt, vocab-half): grid 4096. Each block computes
// the full 64x256 joint (tanh 2x redundant device-wide) into XOR-swizzled
// 32 KB LDS -> 5 blocks/CU, 20 waves, VGPR cap ~102 (headroom for the
// compiler to hoist B-loads across K-steps — the R15 64-VGPR wall removed).
// Wave w owns v-slice vh*256 + [w*64, w*64+64). Epilogue: R15's proven
// LDS-transpose ([16][260] f32 reusing joint region) + coalesced plain
// f32x4 stores.
__global__ __launch_bounds__(256, 5) void joiner_mfma(const float* __restrict__ hf,
                                                      const float* __restrict__ hg,
                                                      const _Float16* __restrict__ w2f,
                                                      float* __restrict__ out) {
    __shared__ char lds[32768];              // joint 64x512B; epi reuses 16640B

    const int tid = threadIdx.x;             // 0..255
    const int bid = blockIdx.x;              // 0..4095
    const int bt = bid >> 1;                 // 0..2047
    const int vh = bid & 1;                  // vocab half
    const int b = bt >> 8;
    const int lane = tid & 63;
    const int w = tid >> 6;                  // wave 0..3
    const int l15 = lane & 15;
    const int lhi = lane >> 4;               // 0..3

    const float* hfrow = hf + (size_t)bt * JD;
    const float* hgb = hg + (size_t)(b * UU) * JD;

    // ---- Phase 1: joint[u][k] = tanh(hf[k] + hg[u][k]) -> fp16, swizzled ----
#pragma unroll
    for (int i = 0; i < 8; ++i) {
        const int task = i * 256 + tid;      // 0..2047
        const int u = task >> 5;             // 0..63
        const int kl = (task & 31) * 8;      // 0..248
        const float* fp = hfrow + kl;
        const float* gp = hgb + (size_t)u * JD + kl;
        float4 f0 = *(const float4*)fp;
        float4 f1 = *(const float4*)(fp + 4);
        float4 g0 = *(const float4*)gp;
        float4 g1 = *(const float4*)(gp + 4);
        float t[8] = {f0.x + g0.x, f0.y + g0.y, f0.z + g0.z, f0.w + g0.w,
                      f1.x + g1.x, f1.y + g1.y, f1.z + g1.z, f1.w + g1.w};
        union { _Float16 h[8]; uint4 v; } p;
#pragma unroll
        for (int j = 0; j < 8; ++j) p.h[j] = (_Float16)fast_tanh(t[j]);
        const int boff = (kl * 2) ^ ((u & 7) << 4);
        *(uint4*)(lds + u * 512 + boff) = p.v;
    }
    __syncthreads();

    // ---- Phase 2: GEMM, 8 K-steps of 32 ----
    f32x4 acc[4][4];
#pragma unroll
    for (int m = 0; m < 4; ++m)
#pragma unroll
        for (int n = 0; n < 4; ++n) acc[m][n] = (f32x4){0.f, 0.f, 0.f, 0.f};

    const int vbase = vh * 256 + w * 64;
#pragma unroll
    for (int ks = 0; ks < 8; ++ks) {
        f16x8 A[4];
        const int off = (ks * 64 + lhi * 16) ^ ((l15 & 7) << 4);
#pragma unroll
        for (int m = 0; m < 4; ++m)
            A[m] = *(const f16x8*)(lds + (m * 16 + l15) * 512 + off);
#pragma unroll
        for (int n = 0; n < 4; ++n) {
            const int v = vbase + n * 16 + l15;      // < 512 (rows >=500 zero)
            f16x8 B = *(const f16x8*)(w2f + (size_t)v * JD + ks * 32 + lhi * 8);
#pragma unroll
            for (int m = 0; m < 4; ++m)
                acc[m][n] = __builtin_amdgcn_mfma_f32_16x16x32_f16(A[m], B, acc[m][n], 0, 0, 0);
        }
    }

    // ---- Epilogue: per m-quadrant, LDS transpose -> coalesced f32x4 stores --
    // fragment element: u = m*16 + lhi*4 + r, local col = w*64 + n*16 + l15
    float* ebuf = (float*)lds;               // viewed as [16][260] f32 (reused)
    float* ob = out + (size_t)bt * UU * VOCAB;
#pragma unroll
    for (int m = 0; m < 4; ++m) {
        __syncthreads();                     // joint reads / prev chunk done
#pragma unroll
        for (int n = 0; n < 4; ++n) {
            const int col = w * 64 + n * 16 + l15;   // 0..255 local
#pragma unroll
            for (int r = 0; r < 4; ++r)
                ebuf[(lhi * 4 + r) * 260 + col] = acc[m][n][r];
        }
        __syncthreads();
#pragma unroll
        for (int it = 0; it < 4; ++it) {
            const int idx = it * 256 + tid;  // 0..1023
            const int row = idx >> 6;        // 0..15
            const int c4 = idx & 63;         // f32x4 within 256-col half
            const int col = vh * 256 + c4 * 4;
            if (col + 3 < VOCAB) {           // vh=1: c4 < 61 (244 cols exactly)
                f32x4 vv = *(const f32x4*)(ebuf + row * 260 + c4 * 4);
                const int u = m * 16 + row;
                *(f32x4*)(ob + (size_t)u * VOCAB + col) = vv;
            }
        }
    }
}

extern "C" void kernel_launch(void* const* d_in, const int* in_sizes, int n_in,
                              void* d_out, int out_size, void* d_ws, size_t ws_size,
                              hipStream_t stream) {
    const float* ft = (const float*)d_in[0];
    const float* gu = (const float*)d_in[1];
    const float* w1 = (const float*)d_in[2];
    const float* w2 = (const float*)d_in[3];
    float* out = (float*)d_out;

    // ws: hf[2048*256] f32 | hg[512*256] f32 | w2f[512*256] fp16
    float* hf = (float*)d_ws;
    float* hg = hf + (size_t)BB * TT * JD;
    _Float16* w2f = (_Float16*)(hg + (size_t)BB * UU * JD);

    joiner_pre<<<352, 256, 0, stream>>>(ft, gu, w1, w2, hf, hg, w2f);
    joiner_mfma<<<(BB * TT) * 2, 256, 0, stream>>>(hf, hg, w2f, out);
}

// Round 20
// 112.959 us; speedup vs baseline: 2.3128x; 2.3128x over previous
//
#include <hip/hip_runtime.h>
#include <math.h>

#define ENC 128
#define PRED 256
#define JD 256      // joiner_dim
#define VOCAB 500
#define NPAD 512
#define BB 8
#define TT 256
#define UU 64

typedef __attribute__((ext_vector_type(8))) _Float16 f16x8;
typedef __attribute__((ext_vector_type(4))) float f32x4;

// branchless tanh: ~8 VALU ops, |err| few ulp (≪ fp16 quantization error).
static __device__ __forceinline__ float fast_tanh(float x) {
    float ax = fabsf(x);
    float e = __expf(2.0f * ax);
    float t = 1.0f - 2.0f / (e + 1.0f);
    return copysignf(t, x);
}

// ---- Kernel A (tiled): blocks 0..255 -> hf (8 rows each), 256..319 -> hg
//      (8 rows each), 320..351 -> w2f convert. Each hf/hg block stages its
//      8 x-rows in LDS and reuses every w1 row-chunk across all 8 outputs.
__global__ __launch_bounds__(256) void joiner_pre(const float* __restrict__ ft,
                                                  const float* __restrict__ gu,
                                                  const float* __restrict__ w1,
                                                  const float* __restrict__ w2,
                                                  float* __restrict__ hf,
                                                  float* __restrict__ hg,
                                                  _Float16* __restrict__ w2f) {
    __shared__ float xs[8 * PRED];           // 8 KB (hf uses 8*128 of it)
    const int bid = blockIdx.x;
    const int tid = threadIdx.x;             // output col j for hf/hg parts

    if (bid < 256) {                         // ---- hf: rows bid*8..+8, K=128
        const int r0 = bid * 8;
        {
            const int row = tid >> 5, c4 = (tid & 31) * 4;   // 8 x 32 float4
            *(float4*)&xs[row * ENC + c4] =
                *(const float4*)(ft + (size_t)(r0 + row) * ENC + c4);
        }
        __syncthreads();
        const float* wr = w1 + tid * (ENC + PRED);
        float acc[8] = {0.f, 0.f, 0.f, 0.f, 0.f, 0.f, 0.f, 0.f};
        for (int k = 0; k < ENC; k += 32) {
            float4 wc[8];
#pragma unroll
            for (int i = 0; i < 8; ++i) wc[i] = *(const float4*)(wr + k + i * 4);
#pragma unroll
            for (int r = 0; r < 8; ++r) {
                const float* xr = xs + r * ENC + k;
                float s = 0.f;
#pragma unroll
                for (int i = 0; i < 8; ++i)
                    s += wc[i].x * xr[i * 4] + wc[i].y * xr[i * 4 + 1] +
                         wc[i].z * xr[i * 4 + 2] + wc[i].w * xr[i * 4 + 3];
                acc[r] += s;
            }
        }
#pragma unroll
        for (int r = 0; r < 8; ++r) hf[(size_t)(r0 + r) * JD + tid] = acc[r];
    } else if (bid < 320) {                  // ---- hg: rows (bid-256)*8, K=256
        const int r0 = (bid - 256) * 8;
#pragma unroll
        for (int h = 0; h < 2; ++h) {
            const int u = h * 256 + tid;     // float4 unit 0..511
            const int row = u >> 6, c4 = (u & 63) * 4;       // 8 x 64 float4
            *(float4*)&xs[row * PRED + c4] =
                *(const float4*)(gu + (size_t)(r0 + row) * PRED + c4);
        }
        __syncthreads();
        const float* wr = w1 + tid * (ENC + PRED) + ENC;
        float acc[8] = {0.f, 0.f, 0.f, 0.f, 0.f, 0.f, 0.f, 0.f};
        for (int k = 0; k < PRED; k += 32) {
            float4 wc[8];
#pragma unroll
            for (int i = 0; i < 8; ++i) wc[i] = *(const float4*)(wr + k + i * 4);
#pragma unroll
            for (int r = 0; r < 8; ++r) {
                const float* xr = xs + r * PRED + k;
                float s = 0.f;
#pragma unroll
                for (int i = 0; i < 8; ++i)
                    s += wc[i].x * xr[i * 4] + wc[i].y * xr[i * 4 + 1] +
                         wc[i].z * xr[i * 4 + 2] + wc[i].w * xr[i * 4 + 3];
                acc[r] += s;
            }
        }
#pragma unroll
        for (int r = 0; r < 8; ++r) hg[(size_t)(r0 + r) * JD + tid] = acc[r];
    } else {                                 // ---- w2f: fp16 convert, pad 512
        const int base = (bid - 320) * 4096; // 16 elems/thread, no row-crossing
        const int e0 = base + tid * 16;
        const int row = e0 >> 8;
        union { _Float16 h[16]; uint4 v[2]; } o;
        if (row < VOCAB) {
#pragma unroll
            for (int i = 0; i < 16; i += 4) {
                float4 f = *(const float4*)(w2 + (size_t)row * JD + (e0 & 255) + i);
                o.h[i] = (_Float16)f.x; o.h[i + 1] = (_Float16)f.y;
                o.h[i + 2] = (_Float16)f.z; o.h[i + 3] = (_Float16)f.w;
            }
        } else {
#pragma unroll
            for (int i = 0; i < 16; ++i) o.h[i] = (_Float16)0.f;
        }
        *(uint4*)(w2f + e0) = o.v[0];
        *(uint4*)(w2f + e0 + 8) = o.v[1];
    }
}

// ---- Kernel B: out = tanh(hf+hg) @ w2^T, single-pass fp16 MFMA ----
// 512 threads (8 waves) per bt. joint 64x256 fp16 in XOR-swizzled LDS (32 KB),
// one barrier, 8 K-steps of 16x16x32 f16 MFMA (wave w owns v in [w*64,w*64+64)),
// then coalesced epilogue: per m-quadrant, fragments -> LDS [16][516] f32,
// barrier, 512 threads stream f32x4 PLAIN stores. One block per bt writes
// exactly 1000 full 128B lines -> no partial-line RFO, single-L2 ownership.
__global__ __launch_bounds__(512, 4) void joiner_mfma(const float* __restrict__ hf,
                                                      const float* __restrict__ hg,
                                                      const _Float16* __restrict__ w2f,
                                                      float* __restrict__ out) {
    __shared__ char lds[33024];              // max(joint 32768, epi 16*516*4)

    const int tid = threadIdx.x;
    const int bt = blockIdx.x;               // 0..2047
    const int b = bt >> 8;
    const int lane = tid & 63;
    const int w = tid >> 6;                  // wave 0..7 -> v base w*64
    const int l15 = lane & 15;
    const int lhi = lane >> 4;               // 0..3

    const float* hfrow = hf + (size_t)bt * JD;
    const float* hgb = hg + (size_t)(b * UU) * JD;

    // ---- Phase 1: joint[u][k] = tanh(hf[k] + hg[u][k]) -> fp16, swizzled ----
#pragma unroll
    for (int i = 0; i < 4; ++i) {
        const int task = i * 512 + tid;      // 0..2047
        const int u = task >> 5;             // 0..63
        const int kl = (task & 31) * 8;      // 0..248
        const float* fp = hfrow + kl;
        const float* gp = hgb + (size_t)u * JD + kl;
        float4 f0 = *(const float4*)fp;
        float4 f1 = *(const float4*)(fp + 4);
        float4 g0 = *(const float4*)gp;
        float4 g1 = *(const float4*)(gp + 4);
        float t[8] = {f0.x + g0.x, f0.y + g0.y, f0.z + g0.z, f0.w + g0.w,
                      f1.x + g1.x, f1.y + g1.y, f1.z + g1.z, f1.w + g1.w};
        union { _Float16 h[8]; uint4 v; } p;
#pragma unroll
        for (int j = 0; j < 8; ++j) p.h[j] = (_Float16)fast_tanh(t[j]);
        const int boff = (kl * 2) ^ ((u & 7) << 4);
        *(uint4*)(lds + u * 512 + boff) = p.v;
    }
    __syncthreads();

    // ---- Phase 2: GEMM, 8 K-steps of 32 ----
    f32x4 acc[4][4];
#pragma unroll
    for (int m = 0; m < 4; ++m)
#pragma unroll
        for (int n = 0; n < 4; ++n) acc[m][n] = (f32x4){0.f, 0.f, 0.f, 0.f};

#pragma unroll
    for (int ks = 0; ks < 8; ++ks) {
        f16x8 A[4];
        const int off = (ks * 64 + lhi * 16) ^ ((l15 & 7) << 4);
#pragma unroll
        for (int m = 0; m < 4; ++m)
            A[m] = *(const f16x8*)(lds + (m * 16 + l15) * 512 + off);
#pragma unroll
        for (int n = 0; n < 4; ++n) {
            const int v = w * 64 + n * 16 + l15;
            f16x8 B = *(const f16x8*)(w2f + (size_t)v * JD + ks * 32 + lhi * 8);
#pragma unroll
            for (int m = 0; m < 4; ++m)
                acc[m][n] = __builtin_amdgcn_mfma_f32_16x16x32_f16(A[m], B, acc[m][n], 0, 0, 0);
        }
    }

    // ---- Epilogue: per m-quadrant, LDS transpose -> coalesced f32x4 stores --
    // fragment element: u = m*16 + lhi*4 + r, v = w*64 + n*16 + l15
    float* ebuf = (float*)lds;               // viewed as [16][516] f32
    float* ob = out + (size_t)bt * UU * VOCAB;
#pragma unroll
    for (int m = 0; m < 4; ++m) {
        __syncthreads();                     // LDS free (joint reads / prev chunk done)
#pragma unroll
        for (int n = 0; n < 4; ++n) {
            const int col = w * 64 + n * 16 + l15;
#pragma unroll
            for (int r = 0; r < 4; ++r)
                ebuf[(lhi * 4 + r) * 516 + col] = acc[m][n][r];
        }
        __syncthreads();
#pragma unroll
        for (int it = 0; it < 4; ++it) {
            const int idx = it * 512 + tid;  // 0..2047
            const int row = idx >> 7;        // 0..15
            const int c4 = idx & 127;        // float4 index in row
            if (c4 < 125) {                  // 125*4 = 500 cols exactly
                f32x4 vv = *(const f32x4*)(ebuf + row * 516 + c4 * 4);
                const int u = m * 16 + row;
                *(f32x4*)(ob + (size_t)u * VOCAB + c4 * 4) = vv;
            }
        }
    }
}

extern "C" void kernel_launch(void* const* d_in, const int* in_sizes, int n_in,
                              void* d_out, int out_size, void* d_ws, size_t ws_size,
                              hipStream_t stream) {
    const float* ft = (const float*)d_in[0];
    const float* gu = (const float*)d_in[1];
    const float* w1 = (const float*)d_in[2];
    const float* w2 = (const float*)d_in[3];
    float* out = (float*)d_out;

    // ws: hf[2048*256] f32 | hg[512*256] f32 | w2f[512*256] fp16
    float* hf = (float*)d_ws;
    float* hg = hf + (size_t)BB * TT * JD;
    _Float16* w2f = (_Float16*)(hg + (size_t)BB * UU * JD);

    joiner_pre<<<352, 256, 0, stream>>>(ft, gu, w1, w2, hf, hg, w2f);
    joiner_mfma<<<BB * TT, 512, 0, stream>>>(hf, hg, w2f, out);
}